// Round 13
// baseline (196.692 us; speedup 1.0000x reference)
//
#include <hip/hip_runtime.h>
#include <hip/hip_bf16.h>
#include <stdint.h>

// Problem constants
#define BB 64      // batch
#define JJ 2048    // input capsules
#define DI 16      // input dim
#define CC 32      // output capsules
#define OO 32      // output dim
#define CO 1024    // CC*OO
#define TJ 16      // j per block
#define NJT 128    // JJ/TJ

static const size_t W2_BYTES = (size_t)CC * JJ * OO * DI * 2;  // 64 MB
static const size_t X3_BYTES = (size_t)BB * JJ * DI * 2;       // 4 MB

typedef _Float16 f16x4 __attribute__((ext_vector_type(4)));
typedef float    f32x4 __attribute__((ext_vector_type(4)));

// __has_builtin on amdgcn builtins is false in the host pass (R7 lesson).
#if defined(__HIP_DEVICE_COMPILE__)
# if __has_builtin(__builtin_amdgcn_mfma_f32_16x16x16f16)
#  define MFMA16(a, b, c) __builtin_amdgcn_mfma_f32_16x16x16f16((a), (b), (c), 0, 0, 0)
# else
#  define MFMA16(a, b, c) __builtin_amdgcn_mfma_f32_16x16x16_f16((a), (b), (c), 0, 0, 0)
# endif
# define SCHED_FENCE() __builtin_amdgcn_sched_barrier(0)
#else
# define MFMA16(a, b, c) (c)
# define SCHED_FENCE()
#endif

union Pack2 { unsigned u; _Float16 h[2]; };

// W [c][j][o][i] f32 -> W2 f16 in A-fragment order (A = W, rows = co, k = i):
// entry E = (j*64 + ct)*64 + l holds, for e=0..3, W[co = ct*16 + (l&15)]
// [i = 4*(l>>4)+e] of column j. 8B per entry, stored as 16B pairs.
__global__ __launch_bounds__(256) void prep_w(const float* __restrict__ W,
                                              uint2* __restrict__ W2) {
  const int j = blockIdx.x;    // 2048
  const int tt = threadIdx.x;  // 256
#pragma unroll
  for (int r = 0; r < 16; ++r) {
    const int s = r * 256 + tt;           // 0..4095 = ct*64 + l
    const int ct = s >> 6, l = s & 63;
    const int co = ct * 16 + (l & 15);
    const int c = co >> 5, o = co & 31;
    const float4 src = ((const float4*)W)[(((size_t)c * JJ + j) * OO + o) * 4 + (l >> 4)];
    Pack2 a, b;
    a.h[0] = (_Float16)src.x; a.h[1] = (_Float16)src.y;
    b.h[0] = (_Float16)src.z; b.h[1] = (_Float16)src.w;
    W2[(size_t)j * 4096 + s] = make_uint2(a.u, b.u);
  }
}

// x [b][j][i] f32 -> X3 f16 in B-fragment order (B = x, cols = b, k = i):
// entry E = ((bq*JJ + j)*2 + bt)*64 + l holds x[b = bq*32 + bt*16 + (l&15)]
// [i = 4*(l>>4)+e], e=0..3.  (bq in 0..1 = 32-b halves)
__global__ __launch_bounds__(256) void prep_x(const float* __restrict__ X,
                                              uint2* __restrict__ X3) {
  const unsigned T = blockIdx.x * 256 + threadIdx.x;   // 524288
  const int l = T & 63, bt = (T >> 6) & 1, j = (T >> 7) & 2047, bq = (int)(T >> 18);
  const int b = bq * 32 + bt * 16 + (l & 15);
  const float4 src = ((const float4*)X)[((size_t)b * JJ + j) * 4 + (l >> 4)];
  Pack2 a, bb;
  a.h[0] = (_Float16)src.x; a.h[1] = (_Float16)src.y;
  bb.h[0] = (_Float16)src.z; bb.h[1] = (_Float16)src.w;
  X3[T] = make_uint2(a.u, bb.u);
}

// MFMA routing pass, c-major GEMM: per j, C[co][b] = W_j[co][i] x x[b][i].
// R13: 512-thr blocks (8 waves), grid NJT*4 = 512 -> 2 blocks/CU (two
// independent barrier domains per CU: one block computes while the other
// waits). Block: 16 b (bq quarter) x 1024 co. Wave w owns ct tiles 8w..8w+7
// (c = 4w..4w+3) -> 8 MFMA(16x16x16)/jj. Lane l = g*16+t: D col t -> b,
// D rows 4g+r -> co. 2 W slabs, stage(jj+2) issued after the post-read
// barrier (all waves' ds_reads drained -> safe to overwrite). lbuf
// parity-dbuf'd. Counted vmcnt(4): slab jj landed, jj+1 in flight.
template<bool HAVE_V>
__global__ __launch_bounds__(512, 4) void route_mfma(
    const uint4* __restrict__ X3, const uint4* __restrict__ W2,
    const float* __restrict__ vsum, float* __restrict__ partial)
{
  __shared__ uint4 wbuf[2][2048];    // 2 x 32KB W slabs (A-frags)
  __shared__ uint4 xbuf[512];        // 8KB: 16 jj x 64 lanes x 8B B-frags
  __shared__ float lbuf[2][16 * 33]; // 16 b-rows x 32 c (+1 pad), jj-parity dbuf

  const int jt   = blockIdx.x & (NJT - 1);
  const int bq4  = blockIdx.x >> 7;   // 0..3: 16-b quarter
  const int tid  = threadIdx.x;
  const int w    = tid >> 6;          // 0..7
  const int lane = tid & 63;
  const int g    = lane >> 4;
  const int t    = lane & 15;

  // vsum[b][c][o] for this lane's 4 c x 8 o (b = bq4*16 + t), packed f16 (16 VGPR)
  unsigned vsh[4][2][2];   // [cc][hh][rp]
  if (HAVE_V) {
#pragma unroll
    for (int cc = 0; cc < 4; ++cc)
#pragma unroll
      for (int hh = 0; hh < 2; ++hh)
#pragma unroll
        for (int rp = 0; rp < 2; ++rp) {
          const float* vp = vsum + (size_t)(bq4 * 16 + t) * CO
                          + (4 * w + cc) * OO + hh * 16 + 4 * g + 2 * rp;
          Pack2 p; p.h[0] = (_Float16)vp[0]; p.h[1] = (_Float16)vp[1];
          vsh[cc][hh][rp] = p.u;
        }
  }

  const uint4* wsrc = W2 + (size_t)jt * TJ * 2048;   // 16B units, 2048/j

#define STAGEW(bufidx, slab) do {                                                 \
    const uint4* sp_ = wsrc + (size_t)(slab) * 2048 + tid;                        \
    uint4* dp_ = &wbuf[bufidx][tid];                                              \
    _Pragma("unroll")                                                             \
    for (int r_ = 0; r_ < 4; ++r_)                                                \
      __builtin_amdgcn_global_load_lds(                                           \
          (const __attribute__((address_space(1))) void*)(sp_ + r_ * 512),        \
          (__attribute__((address_space(3))) void*)(dp_ + r_ * 512), 16, 0, 0);   \
  } while (0)

  // prologue: x B-frags (8 KB, 1 instr/thread) + first two W slabs.
  // x thread map: jjx = tid>>5, q = tid&31 -> uint4 src index
  // ((bq*JJ + j0+jjx)*2 + bt)*32 + q with bq = bq4>>1, bt = bq4&1.
  {
    const int jjx = tid >> 5, q = tid & 31;
    const uint4* xs = X3 + ((size_t)((bq4 >> 1) * JJ + jt * TJ + jjx) * 2 + (bq4 & 1)) * 32 + q;
    __builtin_amdgcn_global_load_lds(
        (const __attribute__((address_space(1))) void*)xs,
        (__attribute__((address_space(3))) void*)&xbuf[tid], 16, 0, 0);
  }
  STAGEW(0, 0);
  STAGEW(1, 1);

  f32x4 acc[8];
#pragma unroll
  for (int k = 0; k < 8; ++k) acc[k] = f32x4{0.f, 0.f, 0.f, 0.f};

  for (int jj = 0; jj < TJ; ++jj) {
    const int bcur = jj & 1;
    // slab jj (and x) landed; slab jj+1 (4 instr) still in flight
    if (jj < TJ - 1) asm volatile("s_waitcnt vmcnt(4) lgkmcnt(0)" ::: "memory");
    else             asm volatile("s_waitcnt vmcnt(0) lgkmcnt(0)" ::: "memory");
    SCHED_FENCE();
    __builtin_amdgcn_s_barrier();

    const uint2* wb2 = (const uint2*)wbuf[bcur];
    const uint2* xb2 = (const uint2*)xbuf;

    f16x4 bf = __builtin_bit_cast(f16x4, xb2[jj * 64 + lane]);
    f16x4 af[8];
#pragma unroll
    for (int k = 0; k < 8; ++k)
      af[k] = __builtin_bit_cast(f16x4, wb2[(w * 8 + k) * 64 + lane]);

    f32x4 uh[8];
#pragma unroll
    for (int k = 0; k < 8; ++k) {
      if (HAVE_V) uh[k] = MFMA16(af[k], bf, (f32x4{0.f, 0.f, 0.f, 0.f}));
      else        acc[k] = MFMA16(af[k], bf, acc[k]);
    }

    if (HAVE_V) {
      // logit[b][c=4w+cc]: 8 in-lane fma + xor16/32 (sum over o)
      float lp[4];
#pragma unroll
      for (int cc = 0; cc < 4; ++cc) {
        float s = 0.f;
#pragma unroll
        for (int hh = 0; hh < 2; ++hh)
#pragma unroll
          for (int rp = 0; rp < 2; ++rp) {
            Pack2 p; p.u = vsh[cc][hh][rp];
            s = fmaf(uh[2 * cc + hh][2 * rp],     (float)p.h[0], s);
            s = fmaf(uh[2 * cc + hh][2 * rp + 1], (float)p.h[1], s);
          }
        s += __shfl_xor(s, 16);
        s += __shfl_xor(s, 32);
        lp[cc] = s;
      }
      // lane writes its cc == g combo (static select, rule 20)
      {
        const float v01 = (g & 1) ? lp[1] : lp[0];
        const float v23 = (g & 1) ? lp[3] : lp[2];
        const float val = (g >> 1) ? v23 : v01;
        lbuf[jj & 1][t * 33 + 4 * w + g] = val;
      }
      asm volatile("s_waitcnt lgkmcnt(0)" ::: "memory");
      SCHED_FENCE();
      __builtin_amdgcn_s_barrier();
      // all waves' ds_reads of wbuf[bcur] retired -> safe to overwrite
      if (jj + 2 < TJ) STAGEW(bcur, jj + 2);

      // row softmax over 32 c (|logit| small; f32 exp safe, no max-sub).
      // wave w owns rows 2w, 2w+1 (32 lanes per row).
      {
        const int row = 2 * w + (lane >> 5);
        const int cc2 = lane & 31;
        float e = __expf(lbuf[jj & 1][row * 33 + cc2]);
        float den = e;
        den += __shfl_xor(den, 1);  den += __shfl_xor(den, 2);
        den += __shfl_xor(den, 4);  den += __shfl_xor(den, 8);
        den += __shfl_xor(den, 16);
        lbuf[jj & 1][row * 33 + cc2] = e / den;
      }
      asm volatile("s_waitcnt lgkmcnt(0)" ::: "memory");
      SCHED_FENCE();
      __builtin_amdgcn_s_barrier();

      float cf[4];
#pragma unroll
      for (int cc = 0; cc < 4; ++cc)
        cf[cc] = lbuf[jj & 1][t * 33 + 4 * w + cc];
#pragma unroll
      for (int k = 0; k < 8; ++k)
#pragma unroll
        for (int r = 0; r < 4; ++r)
          acc[k][r] = fmaf(cf[k >> 1], uh[k][r], acc[k][r]);
      // next jj uses lbuf[(jj+1)&1] (parity dbuf) -> no 3rd barrier needed
    } else {
      // pass 0: drain own ds_reads, sync, then reuse the buffer
      asm volatile("s_waitcnt lgkmcnt(0)" ::: "memory");
      SCHED_FENCE();
      __builtin_amdgcn_s_barrier();
      if (jj + 2 < TJ) STAGEW(bcur, jj + 2);
    }
  }
#undef STAGEW

  // D layout: col = t -> b, rows 4g+r -> co; acc[k] = 4 consecutive co.
  const float cs = HAVE_V ? 1.f : 0.03125f;
#pragma unroll
  for (int k = 0; k < 8; ++k) {
    const int b  = bq4 * 16 + t;
    const int co = (8 * w + k) * 16 + 4 * g;
    float4 v = make_float4(acc[k][0] * cs, acc[k][1] * cs,
                           acc[k][2] * cs, acc[k][3] * cs);
    *(float4*)(partial + ((size_t)jt * BB + b) * CO + co) = v;
  }
}

// ---------------- f32 fallback route (proven R2/R4 path) ----------------
template<bool HAVE_V>
__global__ __launch_bounds__(256, 1) void route_f32(
    const float* __restrict__ X, const float* __restrict__ W,
    const float* __restrict__ vsum, float* __restrict__ partial)
{
  const int jt   = blockIdx.x & 63;
  const int bq   = blockIdx.x >> 6;
  const int tid  = threadIdx.x;
  const int wave = tid >> 6;
  const int lane = tid & 63;
  const int c    = lane & 31;
  const int o0   = (lane >> 5) << 4;
  const int b0   = bq * 16 + wave * 4;

  float acc[4][16];
#pragma unroll
  for (int bl = 0; bl < 4; ++bl)
#pragma unroll
    for (int ol = 0; ol < 16; ++ol) acc[bl][ol] = 0.f;

  const float* wbase = W + ((size_t)c * JJ * OO + (size_t)o0) * DI;

  for (int jj = 0; jj < 32; ++jj) {
    const int j = jt * 32 + jj;
    float xf[4][16];
#pragma unroll
    for (int bl = 0; bl < 4; ++bl) {
      const float4* xpt = (const float4*)(X + ((size_t)(b0 + bl) * JJ + j) * DI);
#pragma unroll
      for (int q = 0; q < 4; ++q) {
        float4 x4 = xpt[q];
        xf[bl][4*q+0] = x4.x; xf[bl][4*q+1] = x4.y;
        xf[bl][4*q+2] = x4.z; xf[bl][4*q+3] = x4.w;
      }
    }
    const float4* wp = (const float4*)(wbase + (size_t)j * OO * DI);
    float tv[4][16];
#pragma unroll
    for (int ol = 0; ol < 16; ++ol) {
      float wf[16];
#pragma unroll
      for (int q = 0; q < 4; ++q) {
        float4 w4 = wp[4*ol + q];
        wf[4*q+0] = w4.x; wf[4*q+1] = w4.y;
        wf[4*q+2] = w4.z; wf[4*q+3] = w4.w;
      }
#pragma unroll
      for (int bl = 0; bl < 4; ++bl) {
        float tt = 0.f;
#pragma unroll
        for (int i = 0; i < 16; ++i) tt = fmaf(wf[i], xf[bl][i], tt);
        if (!HAVE_V) acc[bl][ol] += tt;
        else         tv[bl][ol] = tt;
      }
    }
    if (HAVE_V) {
#pragma unroll
      for (int bl = 0; bl < 4; ++bl) {
        float dsum = 0.f;
        const float4* vp = (const float4*)(vsum + (size_t)(b0 + bl) * CO + c * OO + o0);
#pragma unroll
        for (int q = 0; q < 4; ++q) {
          float4 v4 = vp[q];
          dsum = fmaf(v4.x, tv[bl][4*q+0], dsum);
          dsum = fmaf(v4.y, tv[bl][4*q+1], dsum);
          dsum = fmaf(v4.z, tv[bl][4*q+2], dsum);
          dsum = fmaf(v4.w, tv[bl][4*q+3], dsum);
        }
        dsum += __shfl_xor(dsum, 32);
        float mm = dsum;
#pragma unroll
        for (int s = 16; s >= 1; s >>= 1) mm = fmaxf(mm, __shfl_xor(mm, s));
        float e = __expf(dsum - mm);
        float den = e;
#pragma unroll
        for (int s = 16; s >= 1; s >>= 1) den += __shfl_xor(den, s);
        float coef = e / den;
#pragma unroll
        for (int ol = 0; ol < 16; ++ol)
          acc[bl][ol] = fmaf(coef, tv[bl][ol], acc[bl][ol]);
      }
    }
  }
  const float cs = HAVE_V ? 1.f : 0.03125f;
#pragma unroll
  for (int bl = 0; bl < 4; ++bl) {
    float* pp = partial + ((size_t)jt * BB + (b0 + bl)) * CO + c * OO + o0;
#pragma unroll
    for (int q = 0; q < 4; ++q) {
      float4 w4 = make_float4(acc[bl][4*q+0]*cs, acc[bl][4*q+1]*cs,
                              acc[bl][4*q+2]*cs, acc[bl][4*q+3]*cs);
      ((float4*)pp)[q] = w4;
    }
  }
}

// Sum NJT j-tile partials -> s[b,c,o]; squash over o; maintain vsum / write out.
template<int NJTR>
__global__ __launch_bounds__(256, 1) void reduce_squash(
    const float* __restrict__ partial, float* __restrict__ vsum,
    float* __restrict__ out, int mode)   // 0: vsum = v; 1: vsum += v; 2: out = v
{
  const int idx = blockIdx.x * 256 + threadIdx.x;   // = b*CO + c*OO + o
  float s0 = 0.f, s1 = 0.f, s2 = 0.f, s3 = 0.f;
#pragma unroll 4
  for (int nt = 0; nt < NJTR; nt += 4) {
    s0 += partial[(size_t)(nt + 0) * (BB * CO) + idx];
    s1 += partial[(size_t)(nt + 1) * (BB * CO) + idx];
    s2 += partial[(size_t)(nt + 2) * (BB * CO) + idx];
    s3 += partial[(size_t)(nt + 3) * (BB * CO) + idx];
  }
  float s = (s0 + s1) + (s2 + s3);
  float s2m = s * s;
#pragma unroll
  for (int mk = 16; mk >= 1; mk >>= 1) s2m += __shfl_xor(s2m, mk);
  float scale = s2m / ((1.f + s2m) * sqrtf(s2m + 1e-7f));
  float v = scale * s;
  if (mode == 2)      out[idx] = v;
  else if (mode == 1) vsum[idx] += v;
  else                vsum[idx] = v;
}

static void run_mfma(const float* X, const float* W, float* out,
                     void* d_ws, hipStream_t stream)
{
  uint2* W2      = (uint2*)d_ws;
  uint2* X3      = (uint2*)((char*)d_ws + W2_BYTES);
  float* partial = (float*)((char*)d_ws + W2_BYTES + X3_BYTES);
  float* vsum    = partial + (size_t)NJT * BB * CO;
  const int grid  = NJT * 4;         // 512 blocks of 512 -> 2 blocks/CU
  const int rgrid = BB * CO / 256;

  prep_w<<<JJ, 256, 0, stream>>>(W, W2);
  prep_x<<<2048, 256, 0, stream>>>(X, X3);

  route_mfma<false><<<grid, 512, 0, stream>>>((const uint4*)X3, (const uint4*)W2, nullptr, partial);
  reduce_squash<NJT><<<rgrid, 256, 0, stream>>>(partial, vsum, nullptr, 0);

  route_mfma<true><<<grid, 512, 0, stream>>>((const uint4*)X3, (const uint4*)W2, vsum, partial);
  reduce_squash<NJT><<<rgrid, 256, 0, stream>>>(partial, vsum, nullptr, 1);

  route_mfma<true><<<grid, 512, 0, stream>>>((const uint4*)X3, (const uint4*)W2, vsum, partial);
  reduce_squash<NJT><<<rgrid, 256, 0, stream>>>(partial, vsum, out, 2);
}

static void run_f32_fallback(const float* X, const float* W, float* out,
                             void* d_ws, hipStream_t stream)
{
  float* partial = (float*)d_ws;
  float* vsum    = partial + (size_t)64 * BB * CO;
  const int grid  = 64 * 4;
  const int rgrid = BB * CO / 256;

  route_f32<false><<<grid, 256, 0, stream>>>(X, W, nullptr, partial);
  reduce_squash<64><<<rgrid, 256, 0, stream>>>(partial, vsum, nullptr, 0);
  route_f32<true><<<grid, 256, 0, stream>>>(X, W, vsum, partial);
  reduce_squash<64><<<rgrid, 256, 0, stream>>>(partial, vsum, nullptr, 1);
  route_f32<true><<<grid, 256, 0, stream>>>(X, W, vsum, partial);
  reduce_squash<64><<<rgrid, 256, 0, stream>>>(partial, vsum, out, 2);
}

extern "C" void kernel_launch(void* const* d_in, const int* in_sizes, int n_in,
                              void* d_out, int out_size, void* d_ws, size_t ws_size,
                              hipStream_t stream) {
  (void)in_sizes; (void)n_in; (void)out_size;
  const float* X = (const float*)d_in[0];   // x [64,2048,16] f32
  const float* W = (const float*)d_in[1];   // W [32,2048,32,16] f32
  float* out = (float*)d_out;               // v [64,32,32] f32

  const size_t need = W2_BYTES + X3_BYTES
                    + (size_t)NJT * BB * CO * 4 + (size_t)BB * CO * 4;
  if (ws_size >= need) run_mfma(X, W, out, d_ws, stream);
  else                 run_f32_fallback(X, W, out, d_ws, stream);
}